// Round 10
// baseline (221.810 us; speedup 1.0000x reference)
//
#include <hip/hip_runtime.h>
#include <hip/hip_bf16.h>

#define B_ 2
#define S_ 2048
#define D_ 1024
#define H_ 16
#define DK_ 64

typedef __hip_bfloat16 bf16;
typedef __attribute__((ext_vector_type(8))) short bf16x8;
typedef __attribute__((ext_vector_type(4))) short bf16x4;
typedef __attribute__((ext_vector_type(4))) float f32x4;

// async global->LDS, 16B per lane; LDS dest = wave-uniform base + lane*16
#define GLDS16(g, l)                                                     \
    __builtin_amdgcn_global_load_lds(                                    \
        (const __attribute__((address_space(1))) void*)(g),              \
        (__attribute__((address_space(3))) void*)(l), 16, 0, 0)

#define MFMA_K32(a, b, c) __builtin_amdgcn_mfma_f32_16x16x32_bf16(a, b, c, 0, 0, 0)
#define MFMA_K16(a, b, c) __builtin_amdgcn_mfma_f32_16x16x16bf16_1k(a, b, c, 0, 0, 0)
#define EXP2F(x) __builtin_amdgcn_exp2f(x)

// ---------------- fused f32 -> bf16 convert (all 7 tensors, one launch) ----
__global__ __launch_bounds__(256) void cvt_all(
    const float* __restrict__ q, const float* __restrict__ k, const float* __restrict__ v,
    const float* __restrict__ w0, const float* __restrict__ w1,
    const float* __restrict__ w2, const float* __restrict__ w3,
    bf16* __restrict__ oq, bf16* __restrict__ ok, bf16* __restrict__ ov,
    bf16* __restrict__ o0, bf16* __restrict__ o1, bf16* __restrict__ o2,
    bf16* __restrict__ o3) {
    int bid = blockIdx.x;
    const float* src; bf16* dst; int base;
    if      (bid < 2048) { src = q;  dst = oq; base = bid; }
    else if (bid < 4096) { src = k;  dst = ok; base = bid - 2048; }
    else if (bid < 6144) { src = v;  dst = ov; base = bid - 4096; }
    else if (bid < 6656) { src = w0; dst = o0; base = bid - 6144; }
    else if (bid < 7168) { src = w1; dst = o1; base = bid - 6656; }
    else if (bid < 7680) { src = w2; dst = o2; base = bid - 7168; }
    else                 { src = w3; dst = o3; base = bid - 7680; }
    int i = (base * 256 + threadIdx.x) * 8;
    float4 a = *(const float4*)(src + i);
    float4 b = *(const float4*)(src + i + 4);
    __align__(16) bf16 o[8];
    o[0] = __float2bfloat16(a.x); o[1] = __float2bfloat16(a.y);
    o[2] = __float2bfloat16(a.z); o[3] = __float2bfloat16(a.w);
    o[4] = __float2bfloat16(b.x); o[5] = __float2bfloat16(b.y);
    o[6] = __float2bfloat16(b.z); o[7] = __float2bfloat16(b.w);
    *(bf16x8*)(dst + i) = *(const bf16x8*)o;
}

// ------- shared GEMM main loop: Y = X @ W^T, tile 64m x 128n, BK=32 -------
// 2-buffer __syncthreads structure (verified R5/R9 semantics). 64m tile =
// 24 KB LDS -> 6 blocks/CU = 6 waves/SIMD: the staging drain at each
// barrier is covered by other blocks' compute (TLP, not pipelining).
// Per wave per iter: 8 MFMA + 6 ds_read_b128; 3 GLDS16 per thread.
// 2-bit XOR swizzle on 4 chunks/row: phys = logical ^ (row&3).
__device__ __forceinline__ void proj_loop64m(const bf16* __restrict__ X,
                                             const bf16* __restrict__ W,
                                             int m0, int n0, bf16* As, bf16* Bs,
                                             f32x4 (&acc)[2][4]) {
    const int K = D_;
    const int tid = threadIdx.x;
    const int lane = tid & 63, wave = tid >> 6;
    const int lm = lane & 15, quad = lane >> 4;
    const int wr = wave >> 1, wc = wave & 1;

    auto stage = [&](int t, int bf) {
        int k0 = t * 32;
        bf16* Ab = As + bf * (64 * 32);
        bf16* Bb = Bs + bf * (128 * 32);
        {                                      // A: 64 rows x 4 chunks = 256 slots
            int s = tid;
            int row = s >> 2, c = (s & 3) ^ (row & 3);
            GLDS16(X + (size_t)(m0 + row) * K + k0 + c * 8, Ab + s * 8);
        }
#pragma unroll
        for (int i = 0; i < 2; ++i) {          // B: 128 rows x 4 chunks = 512 slots
            int s = i * 256 + tid;
            int row = s >> 2, c = (s & 3) ^ (row & 3);
            GLDS16(W + (size_t)(n0 + row) * K + k0 + c * 8, Bb + s * 8);
        }
    };

    stage(0, 0);
    for (int t = 0; t < K / 32; ++t) {
        __syncthreads();                    // tile t arrived; other buf free
        if (t + 1 < K / 32) stage(t + 1, (t + 1) & 1);
        const bf16* Ab = As + (t & 1) * (64 * 32);
        const bf16* Bb = Bs + (t & 1) * (128 * 32);
        bf16x8 aF[2], bF[4];
#pragma unroll
        for (int mt = 0; mt < 2; ++mt) {
            int row = wr * 32 + mt * 16 + lm;
            aF[mt] = *(const bf16x8*)(Ab + row * 32 + ((quad ^ (row & 3)) * 8));
        }
#pragma unroll
        for (int nt = 0; nt < 4; ++nt) {
            int row = wc * 64 + nt * 16 + lm;
            bF[nt] = *(const bf16x8*)(Bb + row * 32 + ((quad ^ (row & 3)) * 8));
        }
#pragma unroll
        for (int mt = 0; mt < 2; ++mt)
#pragma unroll
            for (int nt = 0; nt < 4; ++nt)
                acc[mt][nt] = MFMA_K32(aF[mt], bF[nt], acc[mt][nt]);
    }
}

// Q/K/V projections fused: 1D grid 1536 (3z x 64m x 8n), XCD-chunked,
// n-fastest within each chunk. 6 blocks/CU. Per-XCD resident set:
// W (2 MB, L2-pinned) + streaming X panels (128 KB each).
__global__ __launch_bounds__(256) void proj_qkv(
    const bf16* __restrict__ qx, const bf16* __restrict__ kx, const bf16* __restrict__ vx,
    const bf16* __restrict__ wq, const bf16* __restrict__ wk, const bf16* __restrict__ wv,
    bf16* __restrict__ qb, bf16* __restrict__ kb, bf16* __restrict__ vtb) {
    __shared__ __align__(16) bf16 As[2 * 64 * 32];   // 8 KB
    __shared__ __align__(16) bf16 Bs[2 * 128 * 32];  // 16 KB (24 total: 6 blk/CU)
    const int L = (int)blockIdx.x;             // 0..1535, dispatch order
    const int tile = (L & 7) * 192 + (L >> 3); // XCD chunk, bijective (1536%8==0)
    const int z = tile >> 9;                   // 0..2 (512 tiles per z)
    const int rem = tile & 511;
    const int n0 = (rem & 7) * 128;
    const int m0 = (rem >> 3) * 64;
    const bf16* X = (z == 0) ? qx : (z == 1) ? kx : vx;
    const bf16* W = (z == 0) ? wq : (z == 1) ? wk : wv;
    f32x4 acc[2][4] = {};
    proj_loop64m(X, W, m0, n0, As, Bs, acc);

    const int lane = threadIdx.x & 63, wave = threadIdx.x >> 6;
    const int lm = lane & 15, quad = lane >> 4;
    const int wr = wave >> 1, wc = wave & 1;
#pragma unroll
    for (int mt = 0; mt < 2; ++mt) {
        int mbase = m0 + wr * 32 + mt * 16 + quad * 4;
#pragma unroll
        for (int nt = 0; nt < 4; ++nt) {
            int n = n0 + wc * 64 + nt * 16 + lm;
            if (z == 2) {
                // VT[(b*1024 + n)*S + s]: 4 consecutive tokens -> one 8B store
                int b = mbase >> 11, s = mbase & (S_ - 1);
                unsigned short u[4];
#pragma unroll
                for (int r = 0; r < 4; ++r) {
                    bf16 hv = __float2bfloat16(acc[mt][nt][r]);
                    u[r] = *(unsigned short*)&hv;
                }
                ushort4 pk = {u[0], u[1], u[2], u[3]};
                *(ushort4*)(vtb + ((size_t)(b * 1024 + n) * S_ + s)) = pk;
            } else {
                bf16* Y = z ? kb : qb;
#pragma unroll
                for (int r = 0; r < 4; ++r)
                    Y[(size_t)(mbase + r) * D_ + n] = __float2bfloat16(acc[mt][nt][r]);
            }
        }
    }
}

// Output projection: f32 out. 64m x 128n tile, grid 512 = 2 blocks/CU.
// (unchanged; shares proj_loop64m)
__global__ __launch_bounds__(256) void proj_o(const bf16* __restrict__ X,
                                              const bf16* __restrict__ W,
                                              float* __restrict__ Y) {
    __shared__ __align__(16) bf16 As[2 * 64 * 32];   // 8 KB
    __shared__ __align__(16) bf16 Bs[2 * 128 * 32];  // 16 KB
    const int L = (int)blockIdx.x;            // 0..511
    const int tile = (L & 7) * 64 + (L >> 3); // XCD chunk, bijective (512%8==0)
    const int n0 = (tile & 7) * 128;
    const int m0 = (tile >> 3) * 64;
    f32x4 acc[2][4] = {};
    proj_loop64m(X, W, m0, n0, As, Bs, acc);

    const int lane = threadIdx.x & 63, wave = threadIdx.x >> 6;
    const int lm = lane & 15, quad = lane >> 4;
    const int wr = wave >> 1, wc = wave & 1;
#pragma unroll
    for (int mt = 0; mt < 2; ++mt) {
        int mbase = m0 + wr * 32 + mt * 16 + quad * 4;
#pragma unroll
        for (int nt = 0; nt < 4; ++nt) {
            int n = n0 + wc * 64 + nt * 16 + lm;
#pragma unroll
            for (int r = 0; r < 4; ++r)
                Y[(size_t)(mbase + r) * D_ + n] = acc[mt][nt][r];
        }
    }
}

// ------- flash attention, causal, PAIRED q-tiles + j-split 16 waves --------
// (unchanged from R9)
__global__ __launch_bounds__(1024, 4) void attn_kernel(const bf16* __restrict__ Q,
                                                       const bf16* __restrict__ Kb,
                                                       const bf16* __restrict__ VT,
                                                       bf16* __restrict__ O) {
    __shared__ __align__(16) bf16 smem[4 * 128 * 64];  // 64 KB
    bf16* ktb0 = smem;                 // K tiles: 2 x [128][64] chunk-swizzled
    bf16* vtb0 = smem + 2 * 128 * 64;  // V tiles: 2 x [64][128] chunk-swizzled

    const int tid = threadIdx.x;
    const int lane = tid & 63, wave = tid >> 6;   // 0..15
    const int ws = wave & 7, jh = wave >> 3;      // row-slot, j-half
    const int lm = lane & 15, quad = lane >> 4;
    const int f = (int)blockIdx.x;                 // 0..255
    const int cls = f & 7;                         // XCD class
    const int t = f >> 3;                          // 0..31
    const int p = t >> 2;                          // pair index 0..7
    const int combo = cls + 8 * (t & 3);           // (b,h) pinned to class
    const int b = combo >> 4, h = combo & 15;
    const int qiA = p, qiB = 15 - p;
    const int q0A = qiA * 128 + ws * 16;
    const int q0B = qiB * 128 + ws * 16;

    const size_t bhoff = (size_t)b * S_ * D_ + (size_t)h * DK_;
    const bf16* vtg = VT + ((size_t)b * 1024 + h * DK_) * S_;

    // Q fragments (B-operand of S^T MFMA): Q[q=lm][dk=quad*8..]
    const bf16* qpA = Q + bhoff + (size_t)(q0A + lm) * D_ + quad * 8;
    bf16x8 aqA0 = *(const bf16x8*)(qpA);
    bf16x8 aqA1 = *(const bf16x8*)(qpA + 32);
    const bf16* qpB = Q + bhoff + (size_t)(q0B + lm) * D_ + quad * 8;
    bf16x8 aqB0 = *(const bf16x8*)(qpB);
    bf16x8 aqB1 = *(const bf16x8*)(qpB + 32);

    f32x4 oaccA[4] = {}, oaccB[4] = {};
    float lsumA = 0.f, lsumB = 0.f;
    const float cexp = 0.125f * 1.44269504f;  // 1/sqrt(DK) folded into exp2

    auto stage = [&](int i, int bf) {
        int j0s = i * 128;
        {   // K tile 128x64 = 1024 slots of 16B, one per thread
            int s = tid;
            int j = s >> 3, c = (s & 7) ^ (j & 7);
            GLDS16(Kb + bhoff + (size_t)(j0s + j) * D_ + c * 8,
                   ktb0 + bf * (128 * 64) + s * 8);
        }
        {   // V tile 64x128 = 1024 slots
            int s = tid;
            int d = s >> 4, c = (s & 15) ^ (d & 15);
            GLDS16(vtg + (size_t)d * S_ + j0s + c * 8,
                   vtb0 + bf * (64 * 128) + s * 8);
        }
    };

    auto dochunk = [&](bf16x8 bk0, bf16x8 bk1, const bf16x4 (&bv)[4], bool mk,
                       bf16x8 aq0, bf16x8 aq1, f32x4 (&oacc)[4], float& lsum) {
        f32x4 z = {};
        z = MFMA_K32(bk0, aq0, z);
        z = MFMA_K32(bk1, aq1, z);
        bf16x4 pa;
        float rs = 0.f;
#pragma unroll
        for (int r = 0; r < 4; ++r) {
            float pv = EXP2F(z[r] * cexp);
            if (mk && (quad * 4 + r > lm)) pv = 0.f;  // diag: col base == row base
            rs += pv;
            bf16 hv = __float2bfloat16(pv);
            pa[r] = *(short*)&hv;
        }
        lsum += rs;
#pragma unroll
        for (int dt = 0; dt < 4; ++dt)
            oacc[dt] = MFMA_K16(pa, bv[dt], oacc[dt]);
    };

    const int nt = qiB + 1;   // K-tiles staged: 16-p
    stage(0, 0);

    for (int i = 0; i < nt; ++i) {
        __syncthreads();  // tile i present; prev compute done -> other buf free
        if (i + 1 < nt) stage(i + 1, (i + 1) & 1);
        const bf16* ktb = ktb0 + (i & 1) * (128 * 64);
        const bf16* vtl = vtb0 + (i & 1) * (64 * 128);

#pragma unroll
        for (int stl = 0; stl < 4; ++stl) {
            int sg = jh * 4 + stl;   // global chunk 0..7 (wave-uniform)
            // activity masks (all wave-uniform)
            bool actB = (i < qiB) || (sg <= ws);
            bool mkB  = (i == qiB) && (sg == ws);
            bool actA = (i < qiA) || ((i == qiA) && (sg <= ws));
            bool mkA  = (i == qiA) && (sg == ws);
            if (!actB && !actA) continue;

            // shared K/V fragments (depend only on sg, lane)
            int j = sg * 16 + lm;
            bf16x8 bk0 = *(const bf16x8*)(ktb + (((j << 3) | (quad ^ (j & 7))) * 8));
            bf16x8 bk1 = *(const bf16x8*)(ktb + (((j << 3) | ((4 + quad) ^ (j & 7))) * 8));
            bf16x4 bv[4];
#pragma unroll
            for (int dt = 0; dt < 4; ++dt) {
                int d = dt * 16 + lm;
                int cl = sg * 2 + (quad >> 1);
                bv[dt] = *(const bf16x4*)(vtl + d * 128 +
                                          ((cl ^ (d & 15)) * 8 + (quad & 1) * 4));
            }
            if (actB) dochunk(bk0, bk1, bv, mkB, aqB0, aqB1, oaccB, lsumB);
            if (actA) dochunk(bk0, bk1, bv, mkA, aqA0, aqA1, oaccA, lsumA);
        }
    }

    // ---- cross-jh reduction + epilogue (reuse staging LDS as f32 scratch) --
    __syncthreads();   // all LDS reads + pending GLDS writes drained
    float* red = (float*)smem;                 // 8*64*17*4 B = 34.8 KB <= 64 KB
    const int rbase = (ws * 64 + lane) * 17;   // stride 17: bank-spread

    auto reduce_finish = [&](f32x4 (&oacc)[4], float lsum, int q0) {
        if (jh == 1) {
#pragma unroll
            for (int dt = 0; dt < 4; ++dt)
#pragma unroll
                for (int r = 0; r < 4; ++r)
                    red[rbase + dt * 4 + r] = oacc[dt][r];
            red[rbase + 16] = lsum;
        }
        __syncthreads();
        if (jh == 0) {
#pragma unroll
            for (int dt = 0; dt < 4; ++dt)
#pragma unroll
                for (int r = 0; r < 4; ++r)
                    oacc[dt][r] += red[rbase + dt * 4 + r];
            float l = lsum + red[rbase + 16];
            l += __shfl_xor(l, 16, 64);
            l += __shfl_xor(l, 32, 64);   // full row-sum for qrow=q0+lm
#pragma unroll
            for (int r = 0; r < 4; ++r) {
                float inv = 1.f / __shfl(l, quad * 4 + r, 64);
                int qrow = q0 + quad * 4 + r;
#pragma unroll
                for (int dt = 0; dt < 4; ++dt) {
                    int d = dt * 16 + lm;
                    O[bhoff + (size_t)qrow * D_ + d] =
                        __float2bfloat16(oacc[dt][r] * inv);
                }
            }
        }
        __syncthreads();   // red free for next pass
    };
    reduce_finish(oaccB, lsumB, q0B);
    reduce_finish(oaccA, lsumA, q0A);
}

extern "C" void kernel_launch(void* const* d_in, const int* in_sizes, int n_in,
                              void* d_out, int out_size, void* d_ws, size_t ws_size,
                              hipStream_t stream) {
    const float* q_in = (const float*)d_in[0];
    const float* k_in = (const float*)d_in[1];
    const float* v_in = (const float*)d_in[2];
    // d_in[3] = causal mask (int32 tril) -- enforced analytically
    const float* Wq_f = (const float*)d_in[4];
    const float* Wk_f = (const float*)d_in[5];
    const float* Wv_f = (const float*)d_in[6];
    const float* Wo_f = (const float*)d_in[7];
    float* out = (float*)d_out;

    const size_t NEL = (size_t)B_ * S_ * D_;  // 4M
    const size_t WEL = (size_t)D_ * D_;       // 1M
    bf16* p = (bf16*)d_ws;
    bf16* qx = p;  p += NEL;
    bf16* kx = p;  p += NEL;
    bf16* vx = p;  p += NEL;
    bf16* wq = p;  p += WEL;
    bf16* wk = p;  p += WEL;
    bf16* wv = p;  p += WEL;
    bf16* wo = p;  p += WEL;
    bf16* qb = p;  p += NEL;
    bf16* kb = p;  p += NEL;
    bf16* vtb = p; p += NEL;   // transposed V: [(b*1024 + n)][s]
    bf16* cb = p;  p += NEL;

    cvt_all<<<8192, 256, 0, stream>>>(q_in, k_in, v_in, Wq_f, Wk_f, Wv_f, Wo_f,
                                      qx, kx, vx, wq, wk, wv, wo);

    proj_qkv<<<dim3(1536), 256, 0, stream>>>(qx, kx, vx, wq, wk, wv, qb, kb, vtb);

    attn_kernel<<<dim3(256), 1024, 0, stream>>>(qb, kb, vtb, cb);

    proj_o<<<dim3(512), 256, 0, stream>>>(cb, wo, out);
}

// Round 11
// 212.371 us; speedup vs baseline: 1.0444x; 1.0444x over previous
//
#include <hip/hip_runtime.h>
#include <hip/hip_bf16.h>

#define B_ 2
#define S_ 2048
#define D_ 1024
#define H_ 16
#define DK_ 64

typedef __hip_bfloat16 bf16;
typedef __attribute__((ext_vector_type(8))) short bf16x8;
typedef __attribute__((ext_vector_type(4))) short bf16x4;
typedef __attribute__((ext_vector_type(4))) float f32x4;

// async global->LDS, 16B per lane; LDS dest = wave-uniform base + lane*16
#define GLDS16(g, l)                                                     \
    __builtin_amdgcn_global_load_lds(                                    \
        (const __attribute__((address_space(1))) void*)(g),              \
        (__attribute__((address_space(3))) void*)(l), 16, 0, 0)

#define MFMA_K32(a, b, c) __builtin_amdgcn_mfma_f32_16x16x32_bf16(a, b, c, 0, 0, 0)
#define MFMA_K16(a, b, c) __builtin_amdgcn_mfma_f32_16x16x16bf16_1k(a, b, c, 0, 0, 0)
#define EXP2F(x) __builtin_amdgcn_exp2f(x)

// ---------------- fused f32 -> bf16 convert (all 7 tensors, one launch) ----
__global__ __launch_bounds__(256) void cvt_all(
    const float* __restrict__ q, const float* __restrict__ k, const float* __restrict__ v,
    const float* __restrict__ w0, const float* __restrict__ w1,
    const float* __restrict__ w2, const float* __restrict__ w3,
    bf16* __restrict__ oq, bf16* __restrict__ ok, bf16* __restrict__ ov,
    bf16* __restrict__ o0, bf16* __restrict__ o1, bf16* __restrict__ o2,
    bf16* __restrict__ o3) {
    int bid = blockIdx.x;
    const float* src; bf16* dst; int base;
    if      (bid < 2048) { src = q;  dst = oq; base = bid; }
    else if (bid < 4096) { src = k;  dst = ok; base = bid - 2048; }
    else if (bid < 6144) { src = v;  dst = ov; base = bid - 4096; }
    else if (bid < 6656) { src = w0; dst = o0; base = bid - 6144; }
    else if (bid < 7168) { src = w1; dst = o1; base = bid - 6656; }
    else if (bid < 7680) { src = w2; dst = o2; base = bid - 7168; }
    else                 { src = w3; dst = o3; base = bid - 7680; }
    int i = (base * 256 + threadIdx.x) * 8;
    float4 a = *(const float4*)(src + i);
    float4 b = *(const float4*)(src + i + 4);
    __align__(16) bf16 o[8];
    o[0] = __float2bfloat16(a.x); o[1] = __float2bfloat16(a.y);
    o[2] = __float2bfloat16(a.z); o[3] = __float2bfloat16(a.w);
    o[4] = __float2bfloat16(b.x); o[5] = __float2bfloat16(b.y);
    o[6] = __float2bfloat16(b.z); o[7] = __float2bfloat16(b.w);
    *(bf16x8*)(dst + i) = *(const bf16x8*)o;
}

// ------- shared GEMM main loop: Y = X @ W^T, tile 128m x 128n, BK=32 -------
__device__ __forceinline__ void proj_loop32(const bf16* __restrict__ X,
                                            const bf16* __restrict__ W,
                                            int m0, int n0, bf16* As, bf16* Bs,
                                            f32x4 (&acc)[4][4]) {
    const int K = D_;
    const int tid = threadIdx.x;
    const int lane = tid & 63, wave = tid >> 6;
    const int lm = lane & 15, quad = lane >> 4;
    const int wr = wave >> 1, wc = wave & 1;

    auto stage = [&](int t, int bf) {
        int k0 = t * 32;
        bf16* Ab = As + bf * (128 * 32);
        bf16* Bb = Bs + bf * (128 * 32);
#pragma unroll
        for (int i = 0; i < 2; ++i) {          // A: 128 rows x 4 chunks = 512 slots
            int s = i * 256 + tid;
            int row = s >> 2, c = (s & 3) ^ (row & 3);
            GLDS16(X + (size_t)(m0 + row) * K + k0 + c * 8, Ab + s * 8);
        }
#pragma unroll
        for (int i = 0; i < 2; ++i) {          // B: 128 rows x 4 chunks = 512 slots
            int s = i * 256 + tid;
            int row = s >> 2, c = (s & 3) ^ (row & 3);
            GLDS16(W + (size_t)(n0 + row) * K + k0 + c * 8, Bb + s * 8);
        }
    };

    stage(0, 0);
    for (int t = 0; t < K / 32; ++t) {
        __syncthreads();                    // tile t arrived; other buf free
        if (t + 1 < K / 32) stage(t + 1, (t + 1) & 1);
        const bf16* Ab = As + (t & 1) * (128 * 32);
        const bf16* Bb = Bs + (t & 1) * (128 * 32);
        bf16x8 aF[4], bF[4];
#pragma unroll
        for (int mt = 0; mt < 4; ++mt) {
            int row = wr * 64 + mt * 16 + lm;
            aF[mt] = *(const bf16x8*)(Ab + row * 32 + ((quad ^ (row & 3)) * 8));
        }
#pragma unroll
        for (int nt = 0; nt < 4; ++nt) {
            int row = wc * 64 + nt * 16 + lm;
            bF[nt] = *(const bf16x8*)(Bb + row * 32 + ((quad ^ (row & 3)) * 8));
        }
#pragma unroll
        for (int mt = 0; mt < 4; ++mt)
#pragma unroll
            for (int nt = 0; nt < 4; ++nt)
                acc[mt][nt] = MFMA_K32(aF[mt], bF[nt], acc[mt][nt]);
    }
}

// Q/K/V projections fused: 1D grid 768 with z-folded XCD-chunked swizzle.
__global__ __launch_bounds__(256) void proj_qkv(
    const bf16* __restrict__ qx, const bf16* __restrict__ kx, const bf16* __restrict__ vx,
    const bf16* __restrict__ wq, const bf16* __restrict__ wk, const bf16* __restrict__ wv,
    bf16* __restrict__ qb, bf16* __restrict__ kb, bf16* __restrict__ vtb) {
    __shared__ __align__(16) bf16 As[2 * 128 * 32];  // 16 KB
    __shared__ __align__(16) bf16 Bs[2 * 128 * 32];  // 16 KB
    const int L = (int)blockIdx.x;            // 0..767, dispatch order
    const int tile = (L & 7) * 96 + (L >> 3); // XCD chunk, bijective (768%8==0)
    const int z = tile >> 8;                  // 0..2
    const int rem = tile & 255;
    const int n0 = (rem & 7) * 128;
    const int m0 = (rem >> 3) * 128;
    const bf16* X = (z == 0) ? qx : (z == 1) ? kx : vx;
    const bf16* W = (z == 0) ? wq : (z == 1) ? wk : wv;
    f32x4 acc[4][4] = {};
    proj_loop32(X, W, m0, n0, As, Bs, acc);

    const int lane = threadIdx.x & 63, wave = threadIdx.x >> 6;
    const int lm = lane & 15, quad = lane >> 4;
    const int wr = wave >> 1, wc = wave & 1;
#pragma unroll
    for (int mt = 0; mt < 4; ++mt) {
        int mbase = m0 + wr * 64 + mt * 16 + quad * 4;
#pragma unroll
        for (int nt = 0; nt < 4; ++nt) {
            int n = n0 + wc * 64 + nt * 16 + lm;
            if (z == 2) {
                // VT[(b*1024 + n)*S + s]: 4 consecutive tokens -> one 8B store
                int b = mbase >> 11, s = mbase & (S_ - 1);
                unsigned short u[4];
#pragma unroll
                for (int r = 0; r < 4; ++r) {
                    bf16 hv = __float2bfloat16(acc[mt][nt][r]);
                    u[r] = *(unsigned short*)&hv;
                }
                ushort4 pk = {u[0], u[1], u[2], u[3]};
                *(ushort4*)(vtb + ((size_t)(b * 1024 + n) * S_ + s)) = pk;
            } else {
                bf16* Y = z ? kb : qb;
#pragma unroll
                for (int r = 0; r < 4; ++r)
                    Y[(size_t)(mbase + r) * D_ + n] = __float2bfloat16(acc[mt][nt][r]);
            }
        }
    }
}

// Output projection: f32 out. 64m x 128n tile, grid 512 = 2 blocks/CU.
__global__ __launch_bounds__(256) void proj_o(const bf16* __restrict__ X,
                                              const bf16* __restrict__ W,
                                              float* __restrict__ Y) {
    __shared__ __align__(16) bf16 As[2 * 64 * 32];   // 8 KB
    __shared__ __align__(16) bf16 Bs[2 * 128 * 32];  // 16 KB
    const int L = (int)blockIdx.x;            // 0..511
    const int tile = (L & 7) * 64 + (L >> 3); // XCD chunk, bijective (512%8==0)
    const int n0 = (tile & 7) * 128;
    const int m0 = (tile >> 3) * 64;

    const int K = D_;
    const int tid = threadIdx.x;
    const int lane = tid & 63, wave = tid >> 6;
    const int lm = lane & 15, quad = lane >> 4;
    const int wr = wave >> 1, wc = wave & 1;

    f32x4 acc[2][4] = {};

    auto stage = [&](int t, int bf) {
        int k0 = t * 32;
        bf16* Ab = As + bf * (64 * 32);
        bf16* Bb = Bs + bf * (128 * 32);
        {                                      // A: 64 rows x 4 chunks = 256 slots
            int s = tid;
            int row = s >> 2, c = (s & 3) ^ (row & 3);
            GLDS16(X + (size_t)(m0 + row) * K + k0 + c * 8, Ab + s * 8);
        }
#pragma unroll
        for (int i = 0; i < 2; ++i) {          // B: 128 rows x 4 chunks = 512 slots
            int s = i * 256 + tid;
            int row = s >> 2, c = (s & 3) ^ (row & 3);
            GLDS16(W + (size_t)(n0 + row) * K + k0 + c * 8, Bb + s * 8);
        }
    };

    stage(0, 0);
    for (int t = 0; t < K / 32; ++t) {
        __syncthreads();
        if (t + 1 < K / 32) stage(t + 1, (t + 1) & 1);
        const bf16* Ab = As + (t & 1) * (64 * 32);
        const bf16* Bb = Bs + (t & 1) * (128 * 32);
        bf16x8 aF[2], bF[4];
#pragma unroll
        for (int mt = 0; mt < 2; ++mt) {
            int row = wr * 32 + mt * 16 + lm;
            aF[mt] = *(const bf16x8*)(Ab + row * 32 + ((quad ^ (row & 3)) * 8));
        }
#pragma unroll
        for (int nt = 0; nt < 4; ++nt) {
            int row = wc * 64 + nt * 16 + lm;
            bF[nt] = *(const bf16x8*)(Bb + row * 32 + ((quad ^ (row & 3)) * 8));
        }
#pragma unroll
        for (int mt = 0; mt < 2; ++mt)
#pragma unroll
            for (int nt = 0; nt < 4; ++nt)
                acc[mt][nt] = MFMA_K32(aF[mt], bF[nt], acc[mt][nt]);
    }

#pragma unroll
    for (int mt = 0; mt < 2; ++mt) {
        int mbase = m0 + wr * 32 + mt * 16 + quad * 4;
#pragma unroll
        for (int nt = 0; nt < 4; ++nt) {
            int n = n0 + wc * 64 + nt * 16 + lm;
#pragma unroll
            for (int r = 0; r < 4; ++r)
                Y[(size_t)(mbase + r) * D_ + n] = acc[mt][nt][r];
        }
    }
}

// ------- flash attention, causal, PAIRED q-tiles + j-split 16 waves --------
// Block = 1024 thr (16 waves) handles q-tiles p (qiA) and 15-p (qiB) of one
// (b,h): uniform 17 tile-units/block. Wave (ws = wave&7, jh = wave>>3):
// row-slot ws x j-half jh. 4 waves/SIMD hides LDS/VALU latency. K/V
// fragments loaded once per sg and shared by A and B chunk computations.
// Cross-jh partials combined via one LDS reduction pass after the loop.
__global__ __launch_bounds__(1024, 4) void attn_kernel(const bf16* __restrict__ Q,
                                                       const bf16* __restrict__ Kb,
                                                       const bf16* __restrict__ VT,
                                                       bf16* __restrict__ O) {
    __shared__ __align__(16) bf16 smem[4 * 128 * 64];  // 64 KB
    bf16* ktb0 = smem;                 // K tiles: 2 x [128][64] chunk-swizzled
    bf16* vtb0 = smem + 2 * 128 * 64;  // V tiles: 2 x [64][128] chunk-swizzled

    const int tid = threadIdx.x;
    const int lane = tid & 63, wave = tid >> 6;   // 0..15
    const int ws = wave & 7, jh = wave >> 3;      // row-slot, j-half
    const int lm = lane & 15, quad = lane >> 4;
    const int f = (int)blockIdx.x;                 // 0..255
    const int cls = f & 7;                         // XCD class
    const int t = f >> 3;                          // 0..31
    const int p = t >> 2;                          // pair index 0..7
    const int combo = cls + 8 * (t & 3);           // (b,h) pinned to class
    const int b = combo >> 4, h = combo & 15;
    const int qiA = p, qiB = 15 - p;
    const int q0A = qiA * 128 + ws * 16;
    const int q0B = qiB * 128 + ws * 16;

    const size_t bhoff = (size_t)b * S_ * D_ + (size_t)h * DK_;
    const bf16* vtg = VT + ((size_t)b * 1024 + h * DK_) * S_;

    // Q fragments (B-operand of S^T MFMA): Q[q=lm][dk=quad*8..]
    const bf16* qpA = Q + bhoff + (size_t)(q0A + lm) * D_ + quad * 8;
    bf16x8 aqA0 = *(const bf16x8*)(qpA);
    bf16x8 aqA1 = *(const bf16x8*)(qpA + 32);
    const bf16* qpB = Q + bhoff + (size_t)(q0B + lm) * D_ + quad * 8;
    bf16x8 aqB0 = *(const bf16x8*)(qpB);
    bf16x8 aqB1 = *(const bf16x8*)(qpB + 32);

    f32x4 oaccA[4] = {}, oaccB[4] = {};
    float lsumA = 0.f, lsumB = 0.f;
    const float cexp = 0.125f * 1.44269504f;  // 1/sqrt(DK) folded into exp2

    auto stage = [&](int i, int bf) {
        int j0s = i * 128;
        {   // K tile 128x64 = 1024 slots of 16B, one per thread
            int s = tid;
            int j = s >> 3, c = (s & 7) ^ (j & 7);
            GLDS16(Kb + bhoff + (size_t)(j0s + j) * D_ + c * 8,
                   ktb0 + bf * (128 * 64) + s * 8);
        }
        {   // V tile 64x128 = 1024 slots
            int s = tid;
            int d = s >> 4, c = (s & 15) ^ (d & 15);
            GLDS16(vtg + (size_t)d * S_ + j0s + c * 8,
                   vtb0 + bf * (64 * 128) + s * 8);
        }
    };

    auto dochunk = [&](bf16x8 bk0, bf16x8 bk1, const bf16x4 (&bv)[4], bool mk,
                       bf16x8 aq0, bf16x8 aq1, f32x4 (&oacc)[4], float& lsum) {
        f32x4 z = {};
        z = MFMA_K32(bk0, aq0, z);
        z = MFMA_K32(bk1, aq1, z);
        bf16x4 pa;
        float rs = 0.f;
#pragma unroll
        for (int r = 0; r < 4; ++r) {
            float pv = EXP2F(z[r] * cexp);
            if (mk && (quad * 4 + r > lm)) pv = 0.f;  // diag: col base == row base
            rs += pv;
            bf16 hv = __float2bfloat16(pv);
            pa[r] = *(short*)&hv;
        }
        lsum += rs;
#pragma unroll
        for (int dt = 0; dt < 4; ++dt)
            oacc[dt] = MFMA_K16(pa, bv[dt], oacc[dt]);
    };

    const int nt = qiB + 1;   // K-tiles staged: 16-p
    stage(0, 0);

    for (int i = 0; i < nt; ++i) {
        __syncthreads();  // tile i present; prev compute done -> other buf free
        if (i + 1 < nt) stage(i + 1, (i + 1) & 1);
        const bf16* ktb = ktb0 + (i & 1) * (128 * 64);
        const bf16* vtl = vtb0 + (i & 1) * (64 * 128);

#pragma unroll
        for (int stl = 0; stl < 4; ++stl) {
            int sg = jh * 4 + stl;   // global chunk 0..7 (wave-uniform)
            // activity masks (all wave-uniform)
            bool actB = (i < qiB) || (sg <= ws);
            bool mkB  = (i == qiB) && (sg == ws);
            bool actA = (i < qiA) || ((i == qiA) && (sg <= ws));
            bool mkA  = (i == qiA) && (sg == ws);
            if (!actB && !actA) continue;

            // shared K/V fragments (depend only on sg, lane)
            int j = sg * 16 + lm;
            bf16x8 bk0 = *(const bf16x8*)(ktb + (((j << 3) | (quad ^ (j & 7))) * 8));
            bf16x8 bk1 = *(const bf16x8*)(ktb + (((j << 3) | ((4 + quad) ^ (j & 7))) * 8));
            bf16x4 bv[4];
#pragma unroll
            for (int dt = 0; dt < 4; ++dt) {
                int d = dt * 16 + lm;
                int cl = sg * 2 + (quad >> 1);
                bv[dt] = *(const bf16x4*)(vtl + d * 128 +
                                          ((cl ^ (d & 15)) * 8 + (quad & 1) * 4));
            }
            if (actB) dochunk(bk0, bk1, bv, mkB, aqB0, aqB1, oaccB, lsumB);
            if (actA) dochunk(bk0, bk1, bv, mkA, aqA0, aqA1, oaccA, lsumA);
        }
    }

    // ---- cross-jh reduction + epilogue (reuse staging LDS as f32 scratch) --
    __syncthreads();   // all LDS reads + pending GLDS writes drained
    float* red = (float*)smem;                 // 8*64*17*4 B = 34.8 KB <= 64 KB
    const int rbase = (ws * 64 + lane) * 17;   // stride 17: bank-spread

    auto reduce_finish = [&](f32x4 (&oacc)[4], float lsum, int q0) {
        if (jh == 1) {
#pragma unroll
            for (int dt = 0; dt < 4; ++dt)
#pragma unroll
                for (int r = 0; r < 4; ++r)
                    red[rbase + dt * 4 + r] = oacc[dt][r];
            red[rbase + 16] = lsum;
        }
        __syncthreads();
        if (jh == 0) {
#pragma unroll
            for (int dt = 0; dt < 4; ++dt)
#pragma unroll
                for (int r = 0; r < 4; ++r)
                    oacc[dt][r] += red[rbase + dt * 4 + r];
            float l = lsum + red[rbase + 16];
            l += __shfl_xor(l, 16, 64);
            l += __shfl_xor(l, 32, 64);   // full row-sum for qrow=q0+lm
#pragma unroll
            for (int r = 0; r < 4; ++r) {
                float inv = 1.f / __shfl(l, quad * 4 + r, 64);
                int qrow = q0 + quad * 4 + r;
#pragma unroll
                for (int dt = 0; dt < 4; ++dt) {
                    int d = dt * 16 + lm;
                    O[bhoff + (size_t)qrow * D_ + d] =
                        __float2bfloat16(oacc[dt][r] * inv);
                }
            }
        }
        __syncthreads();   // red free for next pass
    };
    reduce_finish(oaccB, lsumB, q0B);
    reduce_finish(oaccA, lsumA, q0A);
}

extern "C" void kernel_launch(void* const* d_in, const int* in_sizes, int n_in,
                              void* d_out, int out_size, void* d_ws, size_t ws_size,
                              hipStream_t stream) {
    const float* q_in = (const float*)d_in[0];
    const float* k_in = (const float*)d_in[1];
    const float* v_in = (const float*)d_in[2];
    // d_in[3] = causal mask (int32 tril) -- enforced analytically
    const float* Wq_f = (const float*)d_in[4];
    const float* Wk_f = (const float*)d_in[5];
    const float* Wv_f = (const float*)d_in[6];
    const float* Wo_f = (const float*)d_in[7];
    float* out = (float*)d_out;

    const size_t NEL = (size_t)B_ * S_ * D_;  // 4M
    const size_t WEL = (size_t)D_ * D_;       // 1M
    bf16* p = (bf16*)d_ws;
    bf16* qx = p;  p += NEL;
    bf16* kx = p;  p += NEL;
    bf16* vx = p;  p += NEL;
    bf16* wq = p;  p += WEL;
    bf16* wk = p;  p += WEL;
    bf16* wv = p;  p += WEL;
    bf16* wo = p;  p += WEL;
    bf16* qb = p;  p += NEL;
    bf16* kb = p;  p += NEL;
    bf16* vtb = p; p += NEL;   // transposed V: [(b*1024 + n)][s]
    bf16* cb = p;  p += NEL;

    cvt_all<<<8192, 256, 0, stream>>>(q_in, k_in, v_in, Wq_f, Wk_f, Wv_f, Wo_f,
                                      qx, kx, vx, wq, wk, wv, wo);

    proj_qkv<<<dim3(768), 256, 0, stream>>>(qx, kx, vx, wq, wk, wv, qb, kb, vtb);

    attn_kernel<<<dim3(256), 1024, 0, stream>>>(qb, kb, vtb, cb);

    proj_o<<<dim3(512), 256, 0, stream>>>(cb, wo, out);
}

// Round 12
// 212.362 us; speedup vs baseline: 1.0445x; 1.0000x over previous
//
#include <hip/hip_runtime.h>
#include <hip/hip_bf16.h>

#define B_ 2
#define S_ 2048
#define D_ 1024
#define H_ 16
#define DK_ 64

typedef __hip_bfloat16 bf16;
typedef __attribute__((ext_vector_type(8))) short bf16x8;
typedef __attribute__((ext_vector_type(4))) short bf16x4;
typedef __attribute__((ext_vector_type(4))) float f32x4;

// async global->LDS, 16B per lane; LDS dest = wave-uniform base + lane*16
#define GLDS16(g, l)                                                     \
    __builtin_amdgcn_global_load_lds(                                    \
        (const __attribute__((address_space(1))) void*)(g),              \
        (__attribute__((address_space(3))) void*)(l), 16, 0, 0)

#define MFMA_K32(a, b, c) __builtin_amdgcn_mfma_f32_16x16x32_bf16(a, b, c, 0, 0, 0)
#define MFMA_K16(a, b, c) __builtin_amdgcn_mfma_f32_16x16x16bf16_1k(a, b, c, 0, 0, 0)
#define EXP2F(x) __builtin_amdgcn_exp2f(x)

// ---------------- fused f32 -> bf16 convert (all 7 tensors, one launch) ----
__global__ __launch_bounds__(256) void cvt_all(
    const float* __restrict__ q, const float* __restrict__ k, const float* __restrict__ v,
    const float* __restrict__ w0, const float* __restrict__ w1,
    const float* __restrict__ w2, const float* __restrict__ w3,
    bf16* __restrict__ oq, bf16* __restrict__ ok, bf16* __restrict__ ov,
    bf16* __restrict__ o0, bf16* __restrict__ o1, bf16* __restrict__ o2,
    bf16* __restrict__ o3) {
    int bid = blockIdx.x;
    const float* src; bf16* dst; int base;
    if      (bid < 2048) { src = q;  dst = oq; base = bid; }
    else if (bid < 4096) { src = k;  dst = ok; base = bid - 2048; }
    else if (bid < 6144) { src = v;  dst = ov; base = bid - 4096; }
    else if (bid < 6656) { src = w0; dst = o0; base = bid - 6144; }
    else if (bid < 7168) { src = w1; dst = o1; base = bid - 6656; }
    else if (bid < 7680) { src = w2; dst = o2; base = bid - 7168; }
    else                 { src = w3; dst = o3; base = bid - 7680; }
    int i = (base * 256 + threadIdx.x) * 8;
    float4 a = *(const float4*)(src + i);
    float4 b = *(const float4*)(src + i + 4);
    __align__(16) bf16 o[8];
    o[0] = __float2bfloat16(a.x); o[1] = __float2bfloat16(a.y);
    o[2] = __float2bfloat16(a.z); o[3] = __float2bfloat16(a.w);
    o[4] = __float2bfloat16(b.x); o[5] = __float2bfloat16(b.y);
    o[6] = __float2bfloat16(b.z); o[7] = __float2bfloat16(b.w);
    *(bf16x8*)(dst + i) = *(const bf16x8*)o;
}

// ------- shared GEMM main loop: Y = X @ W^T, tile 128m x 128n, BK=32 -------
__device__ __forceinline__ void proj_loop32(const bf16* __restrict__ X,
                                            const bf16* __restrict__ W,
                                            int m0, int n0, bf16* As, bf16* Bs,
                                            f32x4 (&acc)[4][4]) {
    const int K = D_;
    const int tid = threadIdx.x;
    const int lane = tid & 63, wave = tid >> 6;
    const int lm = lane & 15, quad = lane >> 4;
    const int wr = wave >> 1, wc = wave & 1;

    auto stage = [&](int t, int bf) {
        int k0 = t * 32;
        bf16* Ab = As + bf * (128 * 32);
        bf16* Bb = Bs + bf * (128 * 32);
#pragma unroll
        for (int i = 0; i < 2; ++i) {          // A: 128 rows x 4 chunks = 512 slots
            int s = i * 256 + tid;
            int row = s >> 2, c = (s & 3) ^ (row & 3);
            GLDS16(X + (size_t)(m0 + row) * K + k0 + c * 8, Ab + s * 8);
        }
#pragma unroll
        for (int i = 0; i < 2; ++i) {          // B: 128 rows x 4 chunks = 512 slots
            int s = i * 256 + tid;
            int row = s >> 2, c = (s & 3) ^ (row & 3);
            GLDS16(W + (size_t)(n0 + row) * K + k0 + c * 8, Bb + s * 8);
        }
    };

    stage(0, 0);
    for (int t = 0; t < K / 32; ++t) {
        __syncthreads();                    // tile t arrived; other buf free
        if (t + 1 < K / 32) stage(t + 1, (t + 1) & 1);
        const bf16* Ab = As + (t & 1) * (128 * 32);
        const bf16* Bb = Bs + (t & 1) * (128 * 32);
        bf16x8 aF[4], bF[4];
#pragma unroll
        for (int mt = 0; mt < 4; ++mt) {
            int row = wr * 64 + mt * 16 + lm;
            aF[mt] = *(const bf16x8*)(Ab + row * 32 + ((quad ^ (row & 3)) * 8));
        }
#pragma unroll
        for (int nt = 0; nt < 4; ++nt) {
            int row = wc * 64 + nt * 16 + lm;
            bF[nt] = *(const bf16x8*)(Bb + row * 32 + ((quad ^ (row & 3)) * 8));
        }
#pragma unroll
        for (int mt = 0; mt < 4; ++mt)
#pragma unroll
            for (int nt = 0; nt < 4; ++nt)
                acc[mt][nt] = MFMA_K32(aF[mt], bF[nt], acc[mt][nt]);
    }
}

// Q/K/V projections fused: 1D grid 768 with z-folded XCD-chunked swizzle.
__global__ __launch_bounds__(256) void proj_qkv(
    const bf16* __restrict__ qx, const bf16* __restrict__ kx, const bf16* __restrict__ vx,
    const bf16* __restrict__ wq, const bf16* __restrict__ wk, const bf16* __restrict__ wv,
    bf16* __restrict__ qb, bf16* __restrict__ kb, bf16* __restrict__ vtb) {
    __shared__ __align__(16) bf16 As[2 * 128 * 32];  // 16 KB
    __shared__ __align__(16) bf16 Bs[2 * 128 * 32];  // 16 KB
    const int L = (int)blockIdx.x;            // 0..767, dispatch order
    const int tile = (L & 7) * 96 + (L >> 3); // XCD chunk, bijective (768%8==0)
    const int z = tile >> 8;                  // 0..2
    const int rem = tile & 255;
    const int n0 = (rem & 7) * 128;
    const int m0 = (rem >> 3) * 128;
    const bf16* X = (z == 0) ? qx : (z == 1) ? kx : vx;
    const bf16* W = (z == 0) ? wq : (z == 1) ? wk : wv;
    f32x4 acc[4][4] = {};
    proj_loop32(X, W, m0, n0, As, Bs, acc);

    const int lane = threadIdx.x & 63, wave = threadIdx.x >> 6;
    const int lm = lane & 15, quad = lane >> 4;
    const int wr = wave >> 1, wc = wave & 1;
#pragma unroll
    for (int mt = 0; mt < 4; ++mt) {
        int mbase = m0 + wr * 64 + mt * 16 + quad * 4;
#pragma unroll
        for (int nt = 0; nt < 4; ++nt) {
            int n = n0 + wc * 64 + nt * 16 + lm;
            if (z == 2) {
                // VT[(b*1024 + n)*S + s]: 4 consecutive tokens -> one 8B store
                int b = mbase >> 11, s = mbase & (S_ - 1);
                unsigned short u[4];
#pragma unroll
                for (int r = 0; r < 4; ++r) {
                    bf16 hv = __float2bfloat16(acc[mt][nt][r]);
                    u[r] = *(unsigned short*)&hv;
                }
                ushort4 pk = {u[0], u[1], u[2], u[3]};
                *(ushort4*)(vtb + ((size_t)(b * 1024 + n) * S_ + s)) = pk;
            } else {
                bf16* Y = z ? kb : qb;
#pragma unroll
                for (int r = 0; r < 4; ++r)
                    Y[(size_t)(mbase + r) * D_ + n] = __float2bfloat16(acc[mt][nt][r]);
            }
        }
    }
}

// Output projection: f32 out. 64m x 128n tile, grid 512 = 2 blocks/CU.
__global__ __launch_bounds__(256) void proj_o(const bf16* __restrict__ X,
                                              const bf16* __restrict__ W,
                                              float* __restrict__ Y) {
    __shared__ __align__(16) bf16 As[2 * 64 * 32];   // 8 KB
    __shared__ __align__(16) bf16 Bs[2 * 128 * 32];  // 16 KB
    const int L = (int)blockIdx.x;            // 0..511
    const int tile = (L & 7) * 64 + (L >> 3); // XCD chunk, bijective (512%8==0)
    const int n0 = (tile & 7) * 128;
    const int m0 = (tile >> 3) * 64;

    const int K = D_;
    const int tid = threadIdx.x;
    const int lane = tid & 63, wave = tid >> 6;
    const int lm = lane & 15, quad = lane >> 4;
    const int wr = wave >> 1, wc = wave & 1;

    f32x4 acc[2][4] = {};

    auto stage = [&](int t, int bf) {
        int k0 = t * 32;
        bf16* Ab = As + bf * (64 * 32);
        bf16* Bb = Bs + bf * (128 * 32);
        {                                      // A: 64 rows x 4 chunks = 256 slots
            int s = tid;
            int row = s >> 2, c = (s & 3) ^ (row & 3);
            GLDS16(X + (size_t)(m0 + row) * K + k0 + c * 8, Ab + s * 8);
        }
#pragma unroll
        for (int i = 0; i < 2; ++i) {          // B: 128 rows x 4 chunks = 512 slots
            int s = i * 256 + tid;
            int row = s >> 2, c = (s & 3) ^ (row & 3);
            GLDS16(W + (size_t)(n0 + row) * K + k0 + c * 8, Bb + s * 8);
        }
    };

    stage(0, 0);
    for (int t = 0; t < K / 32; ++t) {
        __syncthreads();
        if (t + 1 < K / 32) stage(t + 1, (t + 1) & 1);
        const bf16* Ab = As + (t & 1) * (64 * 32);
        const bf16* Bb = Bs + (t & 1) * (128 * 32);
        bf16x8 aF[2], bF[4];
#pragma unroll
        for (int mt = 0; mt < 2; ++mt) {
            int row = wr * 32 + mt * 16 + lm;
            aF[mt] = *(const bf16x8*)(Ab + row * 32 + ((quad ^ (row & 3)) * 8));
        }
#pragma unroll
        for (int nt = 0; nt < 4; ++nt) {
            int row = wc * 64 + nt * 16 + lm;
            bF[nt] = *(const bf16x8*)(Bb + row * 32 + ((quad ^ (row & 3)) * 8));
        }
#pragma unroll
        for (int mt = 0; mt < 2; ++mt)
#pragma unroll
            for (int nt = 0; nt < 4; ++nt)
                acc[mt][nt] = MFMA_K32(aF[mt], bF[nt], acc[mt][nt]);
    }

#pragma unroll
    for (int mt = 0; mt < 2; ++mt) {
        int mbase = m0 + wr * 32 + mt * 16 + quad * 4;
#pragma unroll
        for (int nt = 0; nt < 4; ++nt) {
            int n = n0 + wc * 64 + nt * 16 + lm;
#pragma unroll
            for (int r = 0; r < 4; ++r)
                Y[(size_t)(mbase + r) * D_ + n] = acc[mt][nt][r];
        }
    }
}

// ------- flash attention, causal, PAIRED q-tiles + j-split 16 waves --------
// R9 structure + VALU thinning: the K/V LDS byte-offsets are pure functions
// of (sg, lane) -- loop-invariant across all K-tile iterations. Hoist them
// into statically-indexed register arrays (24 ints: koff0/koff1[4] +
// voff[4][4]) so the inner loop does one add per load instead of the full
// shift/xor/or address chain. VGPR 60 -> ~90 (still 4 waves/SIMD at 1024 thr).
__global__ __launch_bounds__(1024, 4) void attn_kernel(const bf16* __restrict__ Q,
                                                       const bf16* __restrict__ Kb,
                                                       const bf16* __restrict__ VT,
                                                       bf16* __restrict__ O) {
    __shared__ __align__(16) bf16 smem[4 * 128 * 64];  // 64 KB
    bf16* ktb0 = smem;                 // K tiles: 2 x [128][64] chunk-swizzled
    bf16* vtb0 = smem + 2 * 128 * 64;  // V tiles: 2 x [64][128] chunk-swizzled

    const int tid = threadIdx.x;
    const int lane = tid & 63, wave = tid >> 6;   // 0..15
    const int ws = wave & 7, jh = wave >> 3;      // row-slot, j-half
    const int lm = lane & 15, quad = lane >> 4;
    const int f = (int)blockIdx.x;                 // 0..255
    const int cls = f & 7;                         // XCD class
    const int t = f >> 3;                          // 0..31
    const int p = t >> 2;                          // pair index 0..7
    const int combo = cls + 8 * (t & 3);           // (b,h) pinned to class
    const int b = combo >> 4, h = combo & 15;
    const int qiA = p, qiB = 15 - p;
    const int q0A = qiA * 128 + ws * 16;
    const int q0B = qiB * 128 + ws * 16;

    const size_t bhoff = (size_t)b * S_ * D_ + (size_t)h * DK_;
    const bf16* vtg = VT + ((size_t)b * 1024 + h * DK_) * S_;

    // Q fragments (B-operand of S^T MFMA): Q[q=lm][dk=quad*8..]
    const bf16* qpA = Q + bhoff + (size_t)(q0A + lm) * D_ + quad * 8;
    bf16x8 aqA0 = *(const bf16x8*)(qpA);
    bf16x8 aqA1 = *(const bf16x8*)(qpA + 32);
    const bf16* qpB = Q + bhoff + (size_t)(q0B + lm) * D_ + quad * 8;
    bf16x8 aqB0 = *(const bf16x8*)(qpB);
    bf16x8 aqB1 = *(const bf16x8*)(qpB + 32);

    // ---- hoisted LDS offsets: pure functions of (sg, lane), i-invariant ----
    int koff0[4], koff1[4], voff[4][4];
#pragma unroll
    for (int stl = 0; stl < 4; ++stl) {
        int sg = jh * 4 + stl;
        int j = sg * 16 + lm;
        koff0[stl] = ((j << 3) | (quad ^ (j & 7))) * 8;
        koff1[stl] = ((j << 3) | ((4 + quad) ^ (j & 7))) * 8;
        int cl = sg * 2 + (quad >> 1);
#pragma unroll
        for (int dt = 0; dt < 4; ++dt) {
            int d = dt * 16 + lm;
            voff[stl][dt] = d * 128 + ((cl ^ (d & 15)) * 8 + (quad & 1) * 4);
        }
    }

    f32x4 oaccA[4] = {}, oaccB[4] = {};
    float lsumA = 0.f, lsumB = 0.f;
    const float cexp = 0.125f * 1.44269504f;  // 1/sqrt(DK) folded into exp2

    auto stage = [&](int i, int bf) {
        int j0s = i * 128;
        {   // K tile 128x64 = 1024 slots of 16B, one per thread
            int s = tid;
            int j = s >> 3, c = (s & 7) ^ (j & 7);
            GLDS16(Kb + bhoff + (size_t)(j0s + j) * D_ + c * 8,
                   ktb0 + bf * (128 * 64) + s * 8);
        }
        {   // V tile 64x128 = 1024 slots
            int s = tid;
            int d = s >> 4, c = (s & 15) ^ (d & 15);
            GLDS16(vtg + (size_t)d * S_ + j0s + c * 8,
                   vtb0 + bf * (64 * 128) + s * 8);
        }
    };

    auto dochunk = [&](bf16x8 bk0, bf16x8 bk1, const bf16x4 (&bv)[4], bool mk,
                       bf16x8 aq0, bf16x8 aq1, f32x4 (&oacc)[4], float& lsum) {
        f32x4 z = {};
        z = MFMA_K32(bk0, aq0, z);
        z = MFMA_K32(bk1, aq1, z);
        bf16x4 pa;
        float rs = 0.f;
#pragma unroll
        for (int r = 0; r < 4; ++r) {
            float pv = EXP2F(z[r] * cexp);
            if (mk && (quad * 4 + r > lm)) pv = 0.f;  // diag: col base == row base
            rs += pv;
            bf16 hv = __float2bfloat16(pv);
            pa[r] = *(short*)&hv;
        }
        lsum += rs;
#pragma unroll
        for (int dt = 0; dt < 4; ++dt)
            oacc[dt] = MFMA_K16(pa, bv[dt], oacc[dt]);
    };

    const int nt = qiB + 1;   // K-tiles staged: 16-p
    stage(0, 0);

    for (int i = 0; i < nt; ++i) {
        __syncthreads();  // tile i present; prev compute done -> other buf free
        if (i + 1 < nt) stage(i + 1, (i + 1) & 1);
        const bf16* ktb = ktb0 + (i & 1) * (128 * 64);
        const bf16* vtl = vtb0 + (i & 1) * (64 * 128);

#pragma unroll
        for (int stl = 0; stl < 4; ++stl) {
            int sg = jh * 4 + stl;   // global chunk 0..7 (wave-uniform)
            // activity masks (all wave-uniform)
            bool actB = (i < qiB) || (sg <= ws);
            bool mkB  = (i == qiB) && (sg == ws);
            bool actA = (i < qiA) || ((i == qiA) && (sg <= ws));
            bool mkA  = (i == qiA) && (sg == ws);
            if (!actB && !actA) continue;

            // shared K/V fragments via hoisted offsets (one add per load)
            bf16x8 bk0 = *(const bf16x8*)(ktb + koff0[stl]);
            bf16x8 bk1 = *(const bf16x8*)(ktb + koff1[stl]);
            bf16x4 bv[4];
#pragma unroll
            for (int dt = 0; dt < 4; ++dt)
                bv[dt] = *(const bf16x4*)(vtl + voff[stl][dt]);
            if (actB) dochunk(bk0, bk1, bv, mkB, aqB0, aqB1, oaccB, lsumB);
            if (actA) dochunk(bk0, bk1, bv, mkA, aqA0, aqA1, oaccA, lsumA);
        }
    }

    // ---- cross-jh reduction + epilogue (reuse staging LDS as f32 scratch) --
    __syncthreads();   // all LDS reads + pending GLDS writes drained
    float* red = (float*)smem;                 // 8*64*17*4 B = 34.8 KB <= 64 KB
    const int rbase = (ws * 64 + lane) * 17;   // stride 17: bank-spread

    auto reduce_finish = [&](f32x4 (&oacc)[4], float lsum, int q0) {
        if (jh == 1) {
#pragma unroll
            for (int dt = 0; dt < 4; ++dt)
#pragma unroll
                for (int r = 0; r < 4; ++r)
                    red[rbase + dt * 4 + r] = oacc[dt][r];
            red[rbase + 16] = lsum;
        }
        __syncthreads();
        if (jh == 0) {
#pragma unroll
            for (int dt = 0; dt < 4; ++dt)
#pragma unroll
                for (int r = 0; r < 4; ++r)
                    oacc[dt][r] += red[rbase + dt * 4 + r];
            float l = lsum + red[rbase + 16];
            l += __shfl_xor(l, 16, 64);
            l += __shfl_xor(l, 32, 64);   // full row-sum for qrow=q0+lm
#pragma unroll
            for (int r = 0; r < 4; ++r) {
                float inv = 1.f / __shfl(l, quad * 4 + r, 64);
                int qrow = q0 + quad * 4 + r;
#pragma unroll
                for (int dt = 0; dt < 4; ++dt) {
                    int d = dt * 16 + lm;
                    O[bhoff + (size_t)qrow * D_ + d] =
                        __float2bfloat16(oacc[dt][r] * inv);
                }
            }
        }
        __syncthreads();   // red free for next pass
    };
    reduce_finish(oaccB, lsumB, q0B);
    reduce_finish(oaccA, lsumA, q0A);
}

extern "C" void kernel_launch(void* const* d_in, const int* in_sizes, int n_in,
                              void* d_out, int out_size, void* d_ws, size_t ws_size,
                              hipStream_t stream) {
    const float* q_in = (const float*)d_in[0];
    const float* k_in = (const float*)d_in[1];
    const float* v_in = (const float*)d_in[2];
    // d_in[3] = causal mask (int32 tril) -- enforced analytically
    const float* Wq_f = (const float*)d_in[4];
    const float* Wk_f = (const float*)d_in[5];
    const float* Wv_f = (const float*)d_in[6];
    const float* Wo_f = (const float*)d_in[7];
    float* out = (float*)d_out;

    const size_t NEL = (size_t)B_ * S_ * D_;  // 4M
    const size_t WEL = (size_t)D_ * D_;       // 1M
    bf16* p = (bf16*)d_ws;
    bf16* qx = p;  p += NEL;
    bf16* kx = p;  p += NEL;
    bf16* vx = p;  p += NEL;
    bf16* wq = p;  p += WEL;
    bf16* wk = p;  p += WEL;
    bf16* wv = p;  p += WEL;
    bf16* wo = p;  p += WEL;
    bf16* qb = p;  p += NEL;
    bf16* kb = p;  p += NEL;
    bf16* vtb = p; p += NEL;   // transposed V: [(b*1024 + n)][s]
    bf16* cb = p;  p += NEL;

    cvt_all<<<8192, 256, 0, stream>>>(q_in, k_in, v_in, Wq_f, Wk_f, Wv_f, Wo_f,
                                      qx, kx, vx, wq, wk, wv, wo);

    proj_qkv<<<dim3(768), 256, 0, stream>>>(qx, kx, vx, wq, wk, wv, qb, kb, vtb);

    attn_kernel<<<dim3(256), 1024, 0, stream>>>(qb, kb, vtb, cb);

    proj_o<<<dim3(512), 256, 0, stream>>>(cb, wo, out);
}

// Round 14
// 210.531 us; speedup vs baseline: 1.0536x; 1.0087x over previous
//
#include <hip/hip_runtime.h>
#include <hip/hip_bf16.h>

#define B_ 2
#define S_ 2048
#define D_ 1024
#define H_ 16
#define DK_ 64

typedef __hip_bfloat16 bf16;
typedef __attribute__((ext_vector_type(8))) short bf16x8;
typedef __attribute__((ext_vector_type(4))) short bf16x4;
typedef __attribute__((ext_vector_type(4))) float f32x4;

// async global->LDS, 16B per lane; LDS dest = wave-uniform base + lane*16
#define GLDS16(g, l)                                                     \
    __builtin_amdgcn_global_load_lds(                                    \
        (const __attribute__((address_space(1))) void*)(g),              \
        (__attribute__((address_space(3))) void*)(l), 16, 0, 0)

#define MFMA_K32(a, b, c) __builtin_amdgcn_mfma_f32_16x16x32_bf16(a, b, c, 0, 0, 0)
#define MFMA_K16(a, b, c) __builtin_amdgcn_mfma_f32_16x16x16bf16_1k(a, b, c, 0, 0, 0)
#define EXP2F(x) __builtin_amdgcn_exp2f(x)

// ---------------- fused f32 -> bf16 convert (all 7 tensors, one launch) ----
__global__ __launch_bounds__(256) void cvt_all(
    const float* __restrict__ q, const float* __restrict__ k, const float* __restrict__ v,
    const float* __restrict__ w0, const float* __restrict__ w1,
    const float* __restrict__ w2, const float* __restrict__ w3,
    bf16* __restrict__ oq, bf16* __restrict__ ok, bf16* __restrict__ ov,
    bf16* __restrict__ o0, bf16* __restrict__ o1, bf16* __restrict__ o2,
    bf16* __restrict__ o3) {
    int bid = blockIdx.x;
    const float* src; bf16* dst; int base;
    if      (bid < 2048) { src = q;  dst = oq; base = bid; }
    else if (bid < 4096) { src = k;  dst = ok; base = bid - 2048; }
    else if (bid < 6144) { src = v;  dst = ov; base = bid - 4096; }
    else if (bid < 6656) { src = w0; dst = o0; base = bid - 6144; }
    else if (bid < 7168) { src = w1; dst = o1; base = bid - 6656; }
    else if (bid < 7680) { src = w2; dst = o2; base = bid - 7168; }
    else                 { src = w3; dst = o3; base = bid - 7680; }
    int i = (base * 256 + threadIdx.x) * 8;
    float4 a = *(const float4*)(src + i);
    float4 b = *(const float4*)(src + i + 4);
    __align__(16) bf16 o[8];
    o[0] = __float2bfloat16(a.x); o[1] = __float2bfloat16(a.y);
    o[2] = __float2bfloat16(a.z); o[3] = __float2bfloat16(a.w);
    o[4] = __float2bfloat16(b.x); o[5] = __float2bfloat16(b.y);
    o[6] = __float2bfloat16(b.z); o[7] = __float2bfloat16(b.w);
    *(bf16x8*)(dst + i) = *(const bf16x8*)o;
}

// ------- shared GEMM main loop: Y = X @ W^T, tile 128m x 128n, BK=32 -------
// 2-phase gload_lds structure (m97 family). Session-bracketed: counted-vmcnt
// (R6/R7 -25%), reg-staging (R8 -80%), 64m 2xTLP (R10 -20%) all regress;
// 8-phase 256^2 is geometry-blocked (192 tiles < 256 CUs). This is the
// family's measured ceiling (~22% MfmaUtil) at these problem dims.
__device__ __forceinline__ void proj_loop32(const bf16* __restrict__ X,
                                            const bf16* __restrict__ W,
                                            int m0, int n0, bf16* As, bf16* Bs,
                                            f32x4 (&acc)[4][4]) {
    const int K = D_;
    const int tid = threadIdx.x;
    const int lane = tid & 63, wave = tid >> 6;
    const int lm = lane & 15, quad = lane >> 4;
    const int wr = wave >> 1, wc = wave & 1;

    auto stage = [&](int t, int bf) {
        int k0 = t * 32;
        bf16* Ab = As + bf * (128 * 32);
        bf16* Bb = Bs + bf * (128 * 32);
#pragma unroll
        for (int i = 0; i < 2; ++i) {          // A: 128 rows x 4 chunks = 512 slots
            int s = i * 256 + tid;
            int row = s >> 2, c = (s & 3) ^ (row & 3);
            GLDS16(X + (size_t)(m0 + row) * K + k0 + c * 8, Ab + s * 8);
        }
#pragma unroll
        for (int i = 0; i < 2; ++i) {          // B: 128 rows x 4 chunks = 512 slots
            int s = i * 256 + tid;
            int row = s >> 2, c = (s & 3) ^ (row & 3);
            GLDS16(W + (size_t)(n0 + row) * K + k0 + c * 8, Bb + s * 8);
        }
    };

    stage(0, 0);
    for (int t = 0; t < K / 32; ++t) {
        __syncthreads();                    // tile t arrived; other buf free
        if (t + 1 < K / 32) stage(t + 1, (t + 1) & 1);
        const bf16* Ab = As + (t & 1) * (128 * 32);
        const bf16* Bb = Bs + (t & 1) * (128 * 32);
        bf16x8 aF[4], bF[4];
#pragma unroll
        for (int mt = 0; mt < 4; ++mt) {
            int row = wr * 64 + mt * 16 + lm;
            aF[mt] = *(const bf16x8*)(Ab + row * 32 + ((quad ^ (row & 3)) * 8));
        }
#pragma unroll
        for (int nt = 0; nt < 4; ++nt) {
            int row = wc * 64 + nt * 16 + lm;
            bF[nt] = *(const bf16x8*)(Bb + row * 32 + ((quad ^ (row & 3)) * 8));
        }
#pragma unroll
        for (int mt = 0; mt < 4; ++mt)
#pragma unroll
            for (int nt = 0; nt < 4; ++nt)
                acc[mt][nt] = MFMA_K32(aF[mt], bF[nt], acc[mt][nt]);
    }
}

// Q/K/V projections fused: 1D grid 768 with z-folded XCD-chunked swizzle.
// Each XCD gets 96 consecutive tiles (z, m-panel, n), n fastest: W (2MB)
// L2-resident, X panels fetched once per XCD (FETCH 101->22.6 MB, R2).
__global__ __launch_bounds__(256) void proj_qkv(
    const bf16* __restrict__ qx, const bf16* __restrict__ kx, const bf16* __restrict__ vx,
    const bf16* __restrict__ wq, const bf16* __restrict__ wk, const bf16* __restrict__ wv,
    bf16* __restrict__ qb, bf16* __restrict__ kb, bf16* __restrict__ vtb) {
    __shared__ __align__(16) bf16 As[2 * 128 * 32];  // 16 KB
    __shared__ __align__(16) bf16 Bs[2 * 128 * 32];  // 16 KB
    const int L = (int)blockIdx.x;            // 0..767, dispatch order
    const int tile = (L & 7) * 96 + (L >> 3); // XCD chunk, bijective (768%8==0)
    const int z = tile >> 8;                  // 0..2
    const int rem = tile & 255;
    const int n0 = (rem & 7) * 128;
    const int m0 = (rem >> 3) * 128;
    const bf16* X = (z == 0) ? qx : (z == 1) ? kx : vx;
    const bf16* W = (z == 0) ? wq : (z == 1) ? wk : wv;
    f32x4 acc[4][4] = {};
    proj_loop32(X, W, m0, n0, As, Bs, acc);

    const int lane = threadIdx.x & 63, wave = threadIdx.x >> 6;
    const int lm = lane & 15, quad = lane >> 4;
    const int wr = wave >> 1, wc = wave & 1;
#pragma unroll
    for (int mt = 0; mt < 4; ++mt) {
        int mbase = m0 + wr * 64 + mt * 16 + quad * 4;
#pragma unroll
        for (int nt = 0; nt < 4; ++nt) {
            int n = n0 + wc * 64 + nt * 16 + lm;
            if (z == 2) {
                // VT[(b*1024 + n)*S + s]: 4 consecutive tokens -> one 8B store
                int b = mbase >> 11, s = mbase & (S_ - 1);
                unsigned short u[4];
#pragma unroll
                for (int r = 0; r < 4; ++r) {
                    bf16 hv = __float2bfloat16(acc[mt][nt][r]);
                    u[r] = *(unsigned short*)&hv;
                }
                ushort4 pk = {u[0], u[1], u[2], u[3]};
                *(ushort4*)(vtb + ((size_t)(b * 1024 + n) * S_ + s)) = pk;
            } else {
                bf16* Y = z ? kb : qb;
#pragma unroll
                for (int r = 0; r < 4; ++r)
                    Y[(size_t)(mbase + r) * D_ + n] = __float2bfloat16(acc[mt][nt][r]);
            }
        }
    }
}

// Output projection: f32 out. 64m x 128n tile, grid 512 = 2 blocks/CU.
__global__ __launch_bounds__(256) void proj_o(const bf16* __restrict__ X,
                                              const bf16* __restrict__ W,
                                              float* __restrict__ Y) {
    __shared__ __align__(16) bf16 As[2 * 64 * 32];   // 8 KB
    __shared__ __align__(16) bf16 Bs[2 * 128 * 32];  // 16 KB
    const int L = (int)blockIdx.x;            // 0..511
    const int tile = (L & 7) * 64 + (L >> 3); // XCD chunk, bijective (512%8==0)
    const int n0 = (tile & 7) * 128;
    const int m0 = (tile >> 3) * 64;

    const int K = D_;
    const int tid = threadIdx.x;
    const int lane = tid & 63, wave = tid >> 6;
    const int lm = lane & 15, quad = lane >> 4;
    const int wr = wave >> 1, wc = wave & 1;

    f32x4 acc[2][4] = {};

    auto stage = [&](int t, int bf) {
        int k0 = t * 32;
        bf16* Ab = As + bf * (64 * 32);
        bf16* Bb = Bs + bf * (128 * 32);
        {                                      // A: 64 rows x 4 chunks = 256 slots
            int s = tid;
            int row = s >> 2, c = (s & 3) ^ (row & 3);
            GLDS16(X + (size_t)(m0 + row) * K + k0 + c * 8, Ab + s * 8);
        }
#pragma unroll
        for (int i = 0; i < 2; ++i) {          // B: 128 rows x 4 chunks = 512 slots
            int s = i * 256 + tid;
            int row = s >> 2, c = (s & 3) ^ (row & 3);
            GLDS16(W + (size_t)(n0 + row) * K + k0 + c * 8, Bb + s * 8);
        }
    };

    stage(0, 0);
    for (int t = 0; t < K / 32; ++t) {
        __syncthreads();
        if (t + 1 < K / 32) stage(t + 1, (t + 1) & 1);
        const bf16* Ab = As + (t & 1) * (64 * 32);
        const bf16* Bb = Bs + (t & 1) * (128 * 32);
        bf16x8 aF[2], bF[4];
#pragma unroll
        for (int mt = 0; mt < 2; ++mt) {
            int row = wr * 32 + mt * 16 + lm;
            aF[mt] = *(const bf16x8*)(Ab + row * 32 + ((quad ^ (row & 3)) * 8));
        }
#pragma unroll
        for (int nt = 0; nt < 4; ++nt) {
            int row = wc * 64 + nt * 16 + lm;
            bF[nt] = *(const bf16x8*)(Bb + row * 32 + ((quad ^ (row & 3)) * 8));
        }
#pragma unroll
        for (int mt = 0; mt < 2; ++mt)
#pragma unroll
            for (int nt = 0; nt < 4; ++nt)
                acc[mt][nt] = MFMA_K32(aF[mt], bF[nt], acc[mt][nt]);
    }

#pragma unroll
    for (int mt = 0; mt < 2; ++mt) {
        int mbase = m0 + wr * 32 + mt * 16 + quad * 4;
#pragma unroll
        for (int nt = 0; nt < 4; ++nt) {
            int n = n0 + wc * 64 + nt * 16 + lm;
#pragma unroll
            for (int r = 0; r < 4; ++r)
                Y[(size_t)(mbase + r) * D_ + n] = acc[mt][nt][r];
        }
    }
}

// ------- flash attention, causal, PAIRED q-tiles + j-split 16 waves --------
// Block = 1024 thr (16 waves) handles q-tiles p (qiA) and 15-p (qiB) of one
// (b,h): uniform 17 tile-units/block (structural causal balance). Wave
// (ws = wave&7, jh = wave>>3): row-slot ws x j-half jh; 4 waves/SIMD. K/V
// fragments loaded once per sg and shared by A and B chunk computations.
// Cross-jh partials combined via one LDS reduction pass after the loop.
// cls=f&7 pins each bh's 512 KB K/V to one XCD's L2.
__global__ __launch_bounds__(1024, 4) void attn_kernel(const bf16* __restrict__ Q,
                                                       const bf16* __restrict__ Kb,
                                                       const bf16* __restrict__ VT,
                                                       bf16* __restrict__ O) {
    __shared__ __align__(16) bf16 smem[4 * 128 * 64];  // 64 KB
    bf16* ktb0 = smem;                 // K tiles: 2 x [128][64] chunk-swizzled
    bf16* vtb0 = smem + 2 * 128 * 64;  // V tiles: 2 x [64][128] chunk-swizzled

    const int tid = threadIdx.x;
    const int lane = tid & 63, wave = tid >> 6;   // 0..15
    const int ws = wave & 7, jh = wave >> 3;      // row-slot, j-half
    const int lm = lane & 15, quad = lane >> 4;
    const int f = (int)blockIdx.x;                 // 0..255
    const int cls = f & 7;                         // XCD class
    const int t = f >> 3;                          // 0..31
    const int p = t >> 2;                          // pair index 0..7
    const int combo = cls + 8 * (t & 3);           // (b,h) pinned to class
    const int b = combo >> 4, h = combo & 15;
    const int qiA = p, qiB = 15 - p;
    const int q0A = qiA * 128 + ws * 16;
    const int q0B = qiB * 128 + ws * 16;

    const size_t bhoff = (size_t)b * S_ * D_ + (size_t)h * DK_;
    const bf16* vtg = VT + ((size_t)b * 1024 + h * DK_) * S_;

    // Q fragments (B-operand of S^T MFMA): Q[q=lm][dk=quad*8..]
    const bf16* qpA = Q + bhoff + (size_t)(q0A + lm) * D_ + quad * 8;
    bf16x8 aqA0 = *(const bf16x8*)(qpA);
    bf16x8 aqA1 = *(const bf16x8*)(qpA + 32);
    const bf16* qpB = Q + bhoff + (size_t)(q0B + lm) * D_ + quad * 8;
    bf16x8 aqB0 = *(const bf16x8*)(qpB);
    bf16x8 aqB1 = *(const bf16x8*)(qpB + 32);

    f32x4 oaccA[4] = {}, oaccB[4] = {};
    float lsumA = 0.f, lsumB = 0.f;
    const float cexp = 0.125f * 1.44269504f;  // 1/sqrt(DK) folded into exp2

    auto stage = [&](int i, int bf) {
        int j0s = i * 128;
        {   // K tile 128x64 = 1024 slots of 16B, one per thread
            int s = tid;
            int j = s >> 3, c = (s & 7) ^ (j & 7);
            GLDS16(Kb + bhoff + (size_t)(j0s + j) * D_ + c * 8,
                   ktb0 + bf * (128 * 64) + s * 8);
        }
        {   // V tile 64x128 = 1024 slots
            int s = tid;
            int d = s >> 4, c = (s & 15) ^ (d & 15);
            GLDS16(vtg + (size_t)d * S_ + j0s + c * 8,
                   vtb0 + bf * (64 * 128) + s * 8);
        }
    };

    auto dochunk = [&](bf16x8 bk0, bf16x8 bk1, const bf16x4 (&bv)[4], bool mk,
                       bf16x8 aq0, bf16x8 aq1, f32x4 (&oacc)[4], float& lsum) {
        f32x4 z = {};
        z = MFMA_K32(bk0, aq0, z);
        z = MFMA_K32(bk1, aq1, z);
        bf16x4 pa;
        float rs = 0.f;
#pragma unroll
        for (int r = 0; r < 4; ++r) {
            float pv = EXP2F(z[r] * cexp);
            if (mk && (quad * 4 + r > lm)) pv = 0.f;  // diag: col base == row base
            rs += pv;
            bf16 hv = __float2bfloat16(pv);
            pa[r] = *(short*)&hv;
        }
        lsum += rs;
#pragma unroll
        for (int dt = 0; dt < 4; ++dt)
            oacc[dt] = MFMA_K16(pa, bv[dt], oacc[dt]);
    };

    const int nt = qiB + 1;   // K-tiles staged: 16-p
    stage(0, 0);

    for (int i = 0; i < nt; ++i) {
        __syncthreads();  // tile i present; prev compute done -> other buf free
        if (i + 1 < nt) stage(i + 1, (i + 1) & 1);
        const bf16* ktb = ktb0 + (i & 1) * (128 * 64);
        const bf16* vtl = vtb0 + (i & 1) * (64 * 128);

#pragma unroll
        for (int stl = 0; stl < 4; ++stl) {
            int sg = jh * 4 + stl;   // global chunk 0..7 (wave-uniform)
            // activity masks (all wave-uniform)
            bool actB = (i < qiB) || (sg <= ws);
            bool mkB  = (i == qiB) && (sg == ws);
            bool actA = (i < qiA) || ((i == qiA) && (sg <= ws));
            bool mkA  = (i == qiA) && (sg == ws);
            if (!actB && !actA) continue;

            // shared K/V fragments (depend only on sg, lane)
            int j = sg * 16 + lm;
            bf16x8 bk0 = *(const bf16x8*)(ktb + (((j << 3) | (quad ^ (j & 7))) * 8));
            bf16x8 bk1 = *(const bf16x8*)(ktb + (((j << 3) | ((4 + quad) ^ (j & 7))) * 8));
            bf16x4 bv[4];
#pragma unroll
            for (int dt = 0; dt < 4; ++dt) {
                int d = dt * 16 + lm;
                int cl = sg * 2 + (quad >> 1);
                bv[dt] = *(const bf16x4*)(vtl + d * 128 +
                                          ((cl ^ (d & 15)) * 8 + (quad & 1) * 4));
            }
            if (actB) dochunk(bk0, bk1, bv, mkB, aqB0, aqB1, oaccB, lsumB);
            if (actA) dochunk(bk0, bk1, bv, mkA, aqA0, aqA1, oaccA, lsumA);
        }
    }

    // ---- cross-jh reduction + epilogue (reuse staging LDS as f32 scratch) --
    __syncthreads();   // all LDS reads + pending GLDS writes drained
    float* red = (float*)smem;                 // 8*64*17*4 B = 34.8 KB <= 64 KB
    const int rbase = (ws * 64 + lane) * 17;   // stride 17: bank-spread

    auto reduce_finish = [&](f32x4 (&oacc)[4], float lsum, int q0) {
        if (jh == 1) {
#pragma unroll
            for (int dt = 0; dt < 4; ++dt)
#pragma unroll
                for (int r = 0; r < 4; ++r)
                    red[rbase + dt * 4 + r] = oacc[dt][r];
            red[rbase + 16] = lsum;
        }
        __syncthreads();
        if (jh == 0) {
#pragma unroll
            for (int dt = 0; dt < 4; ++dt)
#pragma unroll
                for (int r = 0; r < 4; ++r)
                    oacc[dt][r] += red[rbase + dt * 4 + r];
            float l = lsum + red[rbase + 16];
            l += __shfl_xor(l, 16, 64);
            l += __shfl_xor(l, 32, 64);   // full row-sum for qrow=q0+lm
#pragma unroll
            for (int r = 0; r < 4; ++r) {
                float inv = 1.f / __shfl(l, quad * 4 + r, 64);
                int qrow = q0 + quad * 4 + r;
#pragma unroll
                for (int dt = 0; dt < 4; ++dt) {
                    int d = dt * 16 + lm;
                    O[bhoff + (size_t)qrow * D_ + d] =
                        __float2bfloat16(oacc[dt][r] * inv);
                }
            }
        }
        __syncthreads();   // red free for next pass
    };
    reduce_finish(oaccB, lsumB, q0B);
    reduce_finish(oaccA, lsumA, q0A);
}

extern "C" void kernel_launch(void* const* d_in, const int* in_sizes, int n_in,
                              void* d_out, int out_size, void* d_ws, size_t ws_size,
                              hipStream_t stream) {
    const float* q_in = (const float*)d_in[0];
    const float* k_in = (const float*)d_in[1];
    const float* v_in = (const float*)d_in[2];
    // d_in[3] = causal mask (int32 tril) -- enforced analytically
    const float* Wq_f = (const float*)d_in[4];
    const float* Wk_f = (const float*)d_in[5];
    const float* Wv_f = (const float*)d_in[6];
    const float* Wo_f = (const float*)d_in[7];
    float* out = (float*)d_out;

    const size_t NEL = (size_t)B_ * S_ * D_;  // 4M
    const size_t WEL = (size_t)D_ * D_;       // 1M
    bf16* p = (bf16*)d_ws;
    bf16* qx = p;  p += NEL;
    bf16* kx = p;  p += NEL;
    bf16* vx = p;  p += NEL;
    bf16* wq = p;  p += WEL;
    bf16* wk = p;  p += WEL;
    bf16* wv = p;  p += WEL;
    bf16* wo = p;  p += WEL;
    bf16* qb = p;  p += NEL;
    bf16* kb = p;  p += NEL;
    bf16* vtb = p; p += NEL;   // transposed V: [(b*1024 + n)][s]
    bf16* cb = p;  p += NEL;

    cvt_all<<<8192, 256, 0, stream>>>(q_in, k_in, v_in, Wq_f, Wk_f, Wv_f, Wo_f,
                                      qx, kx, vx, wq, wk, wv, wo);

    proj_qkv<<<dim3(768), 256, 0, stream>>>(qx, kx, vx, wq, wk, wv, qb, kb, vtb);

    attn_kernel<<<dim3(256), 1024, 0, stream>>>(qb, kb, vtb, cb);

    proj_o<<<dim3(512), 256, 0, stream>>>(cb, wo, out);
}